// Round 14
// baseline (255.356 us; speedup 1.0000x reference)
//
#include <hip/hip_runtime.h>
#include <hip/hip_bf16.h>

#define B_ 16
#define S_ 512
#define H_ 768
#define TS_ 20
#define IS_ 20
#define D_ 808
#define M_ 36
#define E_ 12
#define RNUM_ 97
#define D2_ 50
#define P_ (E_*E_)        // 144
#define NODES_ (M_+1)     // 37
#define NCOL_ (D2_*D_)    // 40400
#define MROWS_ (B_*E_)    // 192
#define KSTEPS_ 26
#define KPAD_ (KSTEPS_*32)  // 832
#define BLKPAD_ 1040        // 1024B (4 k-rows x 64 cols fp32) + 16B pad
#define TILEB_ (8*BLKPAD_)  // 8320 B per K-step tile

typedef __attribute__((ext_vector_type(8))) short bf16x8;
typedef __attribute__((ext_vector_type(4))) float f32x4;

__device__ inline unsigned short f2bf(float f) {
  union { float f; unsigned u; } v; v.f = f;
  unsigned r = v.u + 0x7FFFu + ((v.u >> 16) & 1u);
  return (unsigned short)(r >> 16);
}

__device__ inline unsigned pack2bf(float a, float b) {
  union { __hip_bfloat162 h; unsigned u; } p;
  p.h = __float22bfloat162_rn(make_float2(a, b));
  return p.u;
}

__device__ inline void gll16(const float* src, void* lds) {
  __builtin_amdgcn_global_load_lds(
      (const __attribute__((address_space(1))) unsigned int*)src,
      (__attribute__((address_space(3))) unsigned int*)lds, 16, 0, 0);
}

// ---------------- kernel 1: fused pooling -> eswz (mention+entity composed) --
// ent[b,e,d] = tblN[e+1,0]*cls[d] + sum_s w[s]*encC[b,s,d]
//   w[s] = tblN[e+1, midv[s]] / cnt[midv[s]]   (0 if midv[s]==0)
// where tblN = tbl row / row-sum, cnt = token histogram of midv.
// Output written directly as bf16 pre-swizzled eswz (+ zero pad).
__global__ __launch_bounds__(256) void k_pool(
    const float* __restrict__ enc, const int* __restrict__ etype,
    const int* __restrict__ eidv, const int* __restrict__ midv,
    const float* __restrict__ tbl, const float* __restrict__ temb,
    const float* __restrict__ iemb, short* __restrict__ eswz) {
  int blk = blockIdx.x;          // b*12 + e
  int b = blk / E_;
  int e = blk % E_;
  int t = threadIdx.x;
  __shared__ int midS[S_], tyS[S_], ivS[S_];
  __shared__ int cntS[NODES_];
  __shared__ float wmS[NODES_];
  __shared__ float tblS[NODES_];
  __shared__ float invT;
  if (t < NODES_) {
    cntS[t] = 0;
    tblS[t] = tbl[(size_t)(b * (E_ + 1) + (e + 1)) * NODES_ + t];
  }
  __syncthreads();
  for (int s = t; s < S_; s += 256) {
    int m = midv[b * S_ + s];
    midS[s] = m;
    tyS[s]  = etype[b * S_ + s];
    ivS[s]  = eidv[b * S_ + s];
    atomicAdd(&cntS[m], 1);
  }
  __syncthreads();
  if (t == 0) {
    float s = 0.f;
    for (int m = 0; m < NODES_; ++m) s += tblS[m];
    invT = (s > 0.f) ? 1.0f / s : 1.0f;   // ref: tbl unchanged when sum==0
  }
  __syncthreads();
  if (t < NODES_)
    wmS[t] = (t >= 1 && cntS[t] > 0)
                 ? tblS[t] * invT / (float)cntS[t] : 0.0f;
  __syncthreads();

  float a0 = 0.f, a1 = 0.f, a2 = 0.f, a3 = 0.f;
  for (int s = 0; s < S_; ++s) {
    float w = wmS[midS[s]];
    const float* er = enc + (size_t)(b * S_ + s) * H_;
    a0 += w * er[t];
    a1 += w * er[t + 256];
    a2 += w * er[t + 512];
    if (t < TS_ + IS_) {
      int ty = tyS[s], iv = ivS[s];
      a3 += w * ((t < TS_) ? temb[ty * TS_ + t] : iemb[iv * IS_ + (t - TS_)]);
    }
  }
  // cls contribution (node 0): only enc dims
  {
    float w0 = tblS[0] * invT;
    const float* e0 = enc + (size_t)(b * S_) * H_;
    a0 += w0 * e0[t];
    a1 += w0 * e0[t + 256];
    a2 += w0 * e0[t + 512];
  }
  // write eswz: d = t, t+256, t+512, (768+t if t<40); pad d=808..831
  float vals[4] = {a0, a1, a2, a3};
  #pragma unroll
  for (int i = 0; i < 3; ++i) {
    int d = t + i * 256;
    eswz[((size_t)(d >> 3) * MROWS_ + blk) * 8 + (d & 7)] = (short)f2bf(vals[i]);
  }
  if (t < TS_ + IS_) {
    int d = H_ + t;
    eswz[((size_t)(d >> 3) * MROWS_ + blk) * 8 + (d & 7)] = (short)f2bf(a3);
  }
  if (t < KPAD_ - D_) {
    int d = D_ + t;
    eswz[((size_t)(d >> 3) * MROWS_ + blk) * 8 + (d & 7)] = 0;
  }
}

// ---------------- kernel 2: Abf[192,40400] = Ent @ Wview (fused, 1 W pass) ---
__global__ __launch_bounds__(256) void k_gemm(
    const float* __restrict__ Wf, const short* __restrict__ eswz,
    short* __restrict__ Abf) {
  __shared__ __align__(16) char Bs[3 * TILEB_];   // 24.96 KiB
  const int tid = threadIdx.x;
  const int lane = tid & 63;
  const int ln15 = lane & 15;
  const int g = (lane >> 4) & 3;
  const int wv = tid >> 6;
  const int wr = wv >> 1;          // 0..1: row half (96 rows)
  const int wc = wv & 1;           // 0..1: col half (32 cols)
  const int colBase = blockIdx.x * 64;

  f32x4 acc[6][2];
  #pragma unroll
  for (int i = 0; i < 6; ++i)
    #pragma unroll
    for (int j = 0; j < 2; ++j)
      acc[i][j] = (f32x4){0.f, 0.f, 0.f, 0.f};

  auto STAGE = [&](int t, int bufi) {
    #pragma unroll
    for (int r2 = 0; r2 < 2; ++r2) {
      int bi = r2 * 4 + wv;
      int kg = t * 32 + bi * 4 + (lane >> 4);
      if (kg > D_ - 1) kg = D_ - 1;
      int cg = colBase + ln15 * 4;
      if (cg > NCOL_ - 4) cg = NCOL_ - 4;
      gll16(Wf + (size_t)kg * NCOL_ + cg, Bs + bufi * TILEB_ + bi * BLKPAD_);
    }
  };

  STAGE(0, 0);
  STAGE(1, 1);
  __syncthreads();

  int rb = 0;
  for (int t = 0; t < KSTEPS_; ++t) {
    int sb = rb + 2; if (sb >= 3) sb -= 3;
    if (t + 2 < KSTEPS_) STAGE(t + 2, sb);
    const char* bb = Bs + rb * TILEB_;
    bf16x8 bfr[2];
    #pragma unroll
    for (int nt = 0; nt < 2; ++nt) {
      float f[8];
      #pragma unroll
      for (int e = 0; e < 8; ++e) {
        int k = g * 8 + e;
        int col = wc * 32 + nt * 16 + ln15;
        f[e] = *(const float*)(bb + (k >> 2) * BLKPAD_ + (k & 3) * 256 + col * 4);
      }
      union { bf16x8 v; unsigned u[4]; } u;
      #pragma unroll
      for (int e2 = 0; e2 < 4; ++e2)
        u.u[e2] = pack2bf(f[2 * e2], f[2 * e2 + 1]);
      bfr[nt] = u.v;
    }
    bf16x8 af[6];
    #pragma unroll
    for (int mt = 0; mt < 6; ++mt)
      af[mt] = *(const bf16x8*)&eswz[
          ((size_t)(t * 4 + g) * MROWS_ + wr * 96 + mt * 16 + ln15) * 8];
    #pragma unroll
    for (int mt = 0; mt < 6; ++mt)
      #pragma unroll
      for (int nt = 0; nt < 2; ++nt)
        acc[mt][nt] = __builtin_amdgcn_mfma_f32_16x16x32_bf16(
            af[mt], bfr[nt], acc[mt][nt], 0, 0, 0);
    __syncthreads();
    rb = (rb == 2) ? 0 : rb + 1;
  }

  #pragma unroll
  for (int mt = 0; mt < 6; ++mt) {
    int row = wr * 96 + mt * 16 + g * 4;
    #pragma unroll
    for (int nt = 0; nt < 2; ++nt) {
      int col = colBase + wc * 32 + nt * 16 + ln15;
      if (col < NCOL_) {
        #pragma unroll
        for (int j = 0; j < 4; ++j)
          Abf[(size_t)(row + j) * NCOL_ + col] = (short)f2bf(acc[mt][nt][j]);
      }
    }
  }
}

// ---------------- kernel 3: z via MFMA — one wave per (b, r) ---------------
__global__ __launch_bounds__(64) void k_score_z(
    const short* __restrict__ Abf, const short* __restrict__ eswz,
    float* __restrict__ zbuf) {
  int w = blockIdx.x;            // 0..799
  int b = w / D2_;
  int r = w % D2_;
  int lane = threadIdx.x;
  int ln15 = lane & 15;
  int g = lane >> 4;
  int m = b * E_ + ln15;
  if (m > MROWS_ - 1) m = MROWS_ - 1;
  const short* ab = Abf + (size_t)m * NCOL_ + (size_t)r * D_ + g * 8;
  const short* bb = eswz + ((size_t)g * MROWS_ + m) * 8;
  f32x4 acc = (f32x4){0.f, 0.f, 0.f, 0.f};
  #pragma unroll
  for (int t = 0; t < KSTEPS_; ++t) {
    bf16x8 af = *(const bf16x8*)(ab + t * 32);
    bf16x8 bf = *(const bf16x8*)(bb + (size_t)t * 4 * MROWS_ * 8);
    acc = __builtin_amdgcn_mfma_f32_16x16x32_bf16(af, bf, acc, 0, 0, 0);
  }
  if (ln15 < E_ && g < 3) {
    #pragma unroll
    for (int jj = 0; jj < 4; ++jj)
      zbuf[(size_t)(b * E_ + g * 4 + jj) * (D2_ * E_) + r * E_ + ln15] = acc[jj];
  }
}

// ---------------- kernel 4: BN + R projection ------------------------------
__global__ __launch_bounds__(256) void k_out(
    const float* __restrict__ zbuf, const float* __restrict__ Rm,
    const float* __restrict__ gam, const float* __restrict__ bet,
    const float* __restrict__ mu, const float* __restrict__ var,
    float* __restrict__ out) {
  int blk = blockIdx.x;   // b*12+ke
  int t = threadIdx.x;
  __shared__ float zS[D2_ * E_];       // 600
  __shared__ float Rs[RNUM_ * D2_];    // 4850
  for (int i = t; i < D2_ * E_; i += 256) {
    int r = i / E_;
    float z = zbuf[(size_t)blk * (D2_ * E_) + i];
    zS[i] = (z - mu[r]) * rsqrtf(var[r] + 1e-5f) * gam[r] + bet[r];
  }
  for (int i = t; i < RNUM_ * D2_; i += 256) Rs[i] = Rm[i];
  __syncthreads();
  for (int o = t; o < E_ * RNUM_; o += 256) {
    int je = o / RNUM_;
    int k = o % RNUM_;
    float s = 0.f;
    #pragma unroll
    for (int r = 0; r < D2_; ++r) s += zS[r * E_ + je] * Rs[k * D2_ + r];
    out[(size_t)blk * (E_ * RNUM_) + o] = s;
  }
}

extern "C" void kernel_launch(void* const* d_in, const int* in_sizes, int n_in,
                              void* d_out, int out_size, void* d_ws, size_t ws_size,
                              hipStream_t stream) {
  const float* enc  = (const float*)d_in[0];
  const int*  etype = (const int*)d_in[1];
  const int*  eidv  = (const int*)d_in[2];
  const int*  midv  = (const int*)d_in[3];
  const float* tbl  = (const float*)d_in[4];
  const float* temb = (const float*)d_in[5];
  const float* iemb = (const float*)d_in[6];
  const float* W    = (const float*)d_in[7];
  const float* Rm   = (const float*)d_in[8];
  const float* gam  = (const float*)d_in[9];
  const float* bet  = (const float*)d_in[10];
  const float* mu   = (const float*)d_in[11];
  const float* var  = (const float*)d_in[12];

  // ws layout: zbuf | eswz | Abf
  float* ws   = (float*)d_ws;
  float* zbuf = ws;                                           // 115,200 f
  short* eswz = (short*)(zbuf + (size_t)MROWS_ * D2_ * E_);   // 159,744 sh
  short* Abf  = eswz + (size_t)104 * MROWS_ * 8;              // 7,756,800 sh
  float* out  = (float*)d_out;

  hipLaunchKernelGGL(k_pool, dim3(MROWS_), dim3(256), 0, stream,
                     enc, etype, eidv, midv, tbl, temb, iemb, eswz);
  hipLaunchKernelGGL(k_gemm, dim3((NCOL_ + 63) / 64), dim3(256), 0, stream,
                     W, eswz, Abf);
  hipLaunchKernelGGL(k_score_z, dim3(B_ * D2_), dim3(64), 0, stream,
                     Abf, eswz, zbuf);
  hipLaunchKernelGGL(k_out, dim3(MROWS_), dim3(256), 0, stream,
                     zbuf, Rm, gam, bet, mu, var, out);
}

// Round 16
// 126.627 us; speedup vs baseline: 2.0166x; 2.0166x over previous
//
#include <hip/hip_runtime.h>
#include <hip/hip_bf16.h>

#define B_ 16
#define S_ 512
#define H_ 768
#define TS_ 20
#define IS_ 20
#define D_ 808
#define M_ 36
#define E_ 12
#define RNUM_ 97
#define D2_ 50
#define P_ (E_*E_)        // 144
#define NODES_ (M_+1)     // 37
#define NCOL_ (D2_*D_)    // 40400
#define MROWS_ (B_*E_)    // 192
#define KSTEPS_ 26
#define KPAD_ (KSTEPS_*32)  // 832
#define BLKPAD_ 1040        // 1024B (4 k-rows x 64 cols fp32) + 16B pad
#define TILEB_ (8*BLKPAD_)  // 8320 B per K-step tile
#define ZS_ (D2_*E_)        // 600 = z elems per (b,ke)
#define JT_ 13              // ceil(808/64) j-tiles per r
#define CSTRIDE_ 72         // padded bf16 row stride for Cs/Es (144 B)

typedef __attribute__((ext_vector_type(8))) short bf16x8;
typedef __attribute__((ext_vector_type(4))) float f32x4;

__device__ inline unsigned short f2bf(float f) {
  union { float f; unsigned u; } v; v.f = f;
  unsigned r = v.u + 0x7FFFu + ((v.u >> 16) & 1u);
  return (unsigned short)(r >> 16);
}

__device__ inline unsigned pack2bf(float a, float b) {
  union { __hip_bfloat162 h; unsigned u; } p;
  p.h = __float22bfloat162_rn(make_float2(a, b));
  return p.u;
}

__device__ inline void gll16(const float* src, void* lds) {
  __builtin_amdgcn_global_load_lds(
      (const __attribute__((address_space(1))) unsigned int*)src,
      (__attribute__((address_space(3))) unsigned int*)lds, 16, 0, 0);
}

// ---------------- kernel 1: mention mean-pooling (round-10 ballot version) ---
__global__ __launch_bounds__(256) void k_mention_pool(
    const float* __restrict__ enc_hid, const int* __restrict__ etype,
    const int* __restrict__ eidv, const int* __restrict__ midv,
    const float* __restrict__ type_emb, const float* __restrict__ id_emb,
    float* __restrict__ x) {
  int blk = blockIdx.x;
  int b = blk / NODES_;
  int n = blk % NODES_;
  int t = threadIdx.x;
  float* xrow = x + (size_t)(b * NODES_ + n) * D_;
  if (n == 0) {
    for (int d = t; d < D_; d += 256)
      xrow[d] = (d < H_) ? enc_hid[(size_t)(b * S_) * H_ + d] : 0.0f;
    return;
  }
  __shared__ int midS[S_], tyS[S_], ivS[S_], list[S_];
  __shared__ int cntS;
  for (int s = t; s < S_; s += 256) {
    midS[s] = midv[b * S_ + s];
    tyS[s]  = etype[b * S_ + s];
    ivS[s]  = eidv[b * S_ + s];
  }
  __syncthreads();
  if (t < 64) {
    int base = 0;
    #pragma unroll
    for (int c = 0; c < 8; ++c) {
      int s = c * 64 + t;
      bool m = (midS[s] == n);
      unsigned long long bal = __ballot(m);
      int pos = base + __popcll(bal & ((1ULL << t) - 1ULL));
      if (m) list[pos] = s;
      base += __popcll(bal);
    }
    if (t == 0) cntS = base;
  }
  __syncthreads();
  int cnt = cntS;
  float a0 = 0.f, a1 = 0.f, a2 = 0.f, a3 = 0.f;
  for (int i = 0; i < cnt; ++i) {
    int s = list[i];
    const float* er = enc_hid + (size_t)(b * S_ + s) * H_;
    a0 += er[t];
    a1 += er[t + 256];
    a2 += er[t + 512];
    if (t < TS_ + IS_) {
      int ty = tyS[s], iv = ivS[s];
      a3 += (t < TS_) ? type_emb[ty * TS_ + t] : id_emb[iv * IS_ + (t - TS_)];
    }
  }
  float inv = (cnt > 0) ? 1.0f / (float)cnt : 0.0f;
  xrow[t] = a0 * inv;
  xrow[t + 256] = a1 * inv;
  xrow[t + 512] = a2 * inv;
  if (t < TS_ + IS_) xrow[H_ + t] = a3 * inv;
}

// ---------------- kernel 2: entity pooling -> bf16 pre-swizzled eswz ---------
__global__ __launch_bounds__(256) void k_entity_pool(
    const float* __restrict__ x, const float* __restrict__ tbl,
    short* __restrict__ eswz) {
  int blk = blockIdx.x;
  int b = blk / E_;
  int e = blk % E_;
  int t = threadIdx.x;
  const float* trow = tbl + (size_t)(b * (E_ + 1) + (e + 1)) * NODES_;
  __shared__ float w[NODES_];
  __shared__ float sinv;
  if (t < NODES_) w[t] = trow[t];
  __syncthreads();
  if (t == 0) {
    float s = 0.f;
    for (int m = 0; m < NODES_; ++m) s += w[m];
    sinv = (s > 0.f) ? 1.0f / s : 0.0f;
  }
  __syncthreads();
  float inv = sinv;
  for (int d = t; d < D_; d += 256) {
    float a = 0.f;
    for (int m = 0; m < NODES_; ++m)
      a += w[m] * x[(size_t)(b * NODES_ + m) * D_ + d];
    float v = a * inv;
    eswz[((size_t)(d >> 3) * MROWS_ + blk) * 8 + (d & 7)] = (short)f2bf(v);
  }
  if (t < KPAD_ - D_) {
    int d = D_ + t;
    eswz[((size_t)(d >> 3) * MROWS_ + blk) * 8 + (d & 7)] = 0;
  }
}

// ---------------- kernel 3: gemm + fused tail contraction --------------------
// block (jt, r): C[192 x 64] = Ent @ Wview[:, r*808+jt*64 ...], then
// zpart[jt][(b,ke)][r*12+je] = sum_{j in tile} C[(b,ke),j] * ent[(b,je),j]
// via in-LDS bf16 mini-MFMAs. Abf intermediate eliminated.
// (round-15 bug fixed: LDS union sized in SHORTS -> 55296 B, not 27648)
__global__ __launch_bounds__(256) void k_gemm(
    const float* __restrict__ Wf, const short* __restrict__ eswz,
    float* __restrict__ zpart) {
  __shared__ __align__(16) short smem_s[2 * CSTRIDE_ * MROWS_];  // 55296 B
  char* smem = (char*)smem_s;
  const int tid = threadIdx.x;
  const int lane = tid & 63;
  const int ln15 = lane & 15;
  const int g = (lane >> 4) & 3;
  const int wv = tid >> 6;
  const int wr = wv >> 1;          // 0..1: row half (96 rows)
  const int wc = wv & 1;           // 0..1: col half (32 cols)
  const int jt = blockIdx.x;       // 0..12
  const int r  = blockIdx.y;       // 0..49
  const int colBase = r * D_ + jt * 64;
  const int colMax  = r * D_ + D_ - 4;

  f32x4 acc[6][2];
  #pragma unroll
  for (int i = 0; i < 6; ++i)
    #pragma unroll
    for (int j = 0; j < 2; ++j)
      acc[i][j] = (f32x4){0.f, 0.f, 0.f, 0.f};

  auto STAGE = [&](int t, int bufi) {
    #pragma unroll
    for (int r2 = 0; r2 < 2; ++r2) {
      int bi = r2 * 4 + wv;
      int kg = t * 32 + bi * 4 + (lane >> 4);
      if (kg > D_ - 1) kg = D_ - 1;
      int cg = colBase + ln15 * 4;
      if (cg > colMax) cg = colMax;          // jt=12 tail clamp (gated later)
      gll16(Wf + (size_t)kg * NCOL_ + cg, smem + bufi * TILEB_ + bi * BLKPAD_);
    }
  };

  STAGE(0, 0);
  STAGE(1, 1);
  __syncthreads();

  int rb = 0;
  for (int t = 0; t < KSTEPS_; ++t) {
    int sb = rb + 2; if (sb >= 3) sb -= 3;
    if (t + 2 < KSTEPS_) STAGE(t + 2, sb);
    const char* bb = smem + rb * TILEB_;
    bf16x8 bfr[2];
    #pragma unroll
    for (int nt = 0; nt < 2; ++nt) {
      float f[8];
      #pragma unroll
      for (int e = 0; e < 8; ++e) {
        int k = g * 8 + e;
        int col = wc * 32 + nt * 16 + ln15;
        f[e] = *(const float*)(bb + (k >> 2) * BLKPAD_ + (k & 3) * 256 + col * 4);
      }
      union { bf16x8 v; unsigned u[4]; } u;
      #pragma unroll
      for (int e2 = 0; e2 < 4; ++e2)
        u.u[e2] = pack2bf(f[2 * e2], f[2 * e2 + 1]);
      bfr[nt] = u.v;
    }
    bf16x8 af[6];
    #pragma unroll
    for (int mt = 0; mt < 6; ++mt)
      af[mt] = *(const bf16x8*)&eswz[
          ((size_t)(t * 4 + g) * MROWS_ + wr * 96 + mt * 16 + ln15) * 8];
    #pragma unroll
    for (int mt = 0; mt < 6; ++mt)
      #pragma unroll
      for (int nt = 0; nt < 2; ++nt)
        acc[mt][nt] = __builtin_amdgcn_mfma_f32_16x16x32_bf16(
            af[mt], bfr[nt], acc[mt][nt], 0, 0, 0);
    __syncthreads();
    rb = (rb == 2) ? 0 : rb + 1;
  }

  // -------- fused epilogue: contract over this tile's 64 j columns --------
  short* Cs = smem_s;                         // [192][72] bf16
  short* Es = smem_s + CSTRIDE_ * MROWS_;     // [192][72] bf16
  __syncthreads();   // staging loads all consumed; safe to repurpose

  // C -> bf16 LDS (gate jt=12 tail: j >= 808 contributes 0)
  #pragma unroll
  for (int mt = 0; mt < 6; ++mt) {
    int row = wr * 96 + mt * 16 + g * 4;
    #pragma unroll
    for (int nt = 0; nt < 2; ++nt) {
      int jl = wc * 32 + nt * 16 + ln15;
      bool ok = (jt * 64 + jl) < D_;
      #pragma unroll
      for (int j = 0; j < 4; ++j)
        Cs[(row + j) * CSTRIDE_ + jl] = ok ? (short)f2bf(acc[mt][nt][j])
                                           : (short)0;
    }
  }
  // ent tile -> Es (from eswz slices jt*8 .. jt*8+7; zero-padded j>=808)
  for (int v = tid; v < 8 * MROWS_; v += 256) {
    int si = v / MROWS_;
    int row = v - si * MROWS_;
    bf16x8 ev = *(const bf16x8*)&eswz[((size_t)(jt * 8 + si) * MROWS_ + row) * 8];
    *(bf16x8*)&Es[row * CSTRIDE_ + si * 8] = ev;
  }
  __syncthreads();

  // mini-MFMAs: per wave 4 batches, D[i,je] = sum_j C[(b,i),j]*ent[(b,je),j]
  #pragma unroll
  for (int bb = 0; bb < 4; ++bb) {
    int b = wv * 4 + bb;
    int rowL = b * E_ + ln15;
    if (rowL > MROWS_ - 1) rowL = MROWS_ - 1;   // pad lanes (unused outputs)
    f32x4 z2 = (f32x4){0.f, 0.f, 0.f, 0.f};
    #pragma unroll
    for (int ks = 0; ks < 2; ++ks) {
      bf16x8 af = *(const bf16x8*)&Cs[rowL * CSTRIDE_ + ks * 32 + g * 8];
      bf16x8 bf = *(const bf16x8*)&Es[rowL * CSTRIDE_ + ks * 32 + g * 8];
      z2 = __builtin_amdgcn_mfma_f32_16x16x32_bf16(af, bf, z2, 0, 0, 0);
    }
    if (ln15 < E_ && g < 3) {
      #pragma unroll
      for (int jj = 0; jj < 4; ++jj) {
        int ke = g * 4 + jj;
        zpart[((size_t)jt * MROWS_ + b * E_ + ke) * ZS_ + r * E_ + ln15] =
            z2[jj];
      }
    }
  }
}

// ---------------- kernel 4: reduce partials + BN + R projection --------------
__global__ __launch_bounds__(256) void k_out(
    const float* __restrict__ zpart, const float* __restrict__ Rm,
    const float* __restrict__ gam, const float* __restrict__ bet,
    const float* __restrict__ mu, const float* __restrict__ var,
    float* __restrict__ out) {
  int blk = blockIdx.x;   // b*12+ke
  int t = threadIdx.x;
  __shared__ float zS[ZS_];            // 600
  __shared__ float Rs[RNUM_ * D2_];    // 4850
  for (int i = t; i < ZS_; i += 256) {
    float s = 0.f;
    #pragma unroll
    for (int jt = 0; jt < JT_; ++jt)
      s += zpart[((size_t)jt * MROWS_ + blk) * ZS_ + i];
    int r = i / E_;
    zS[i] = (s - mu[r]) * rsqrtf(var[r] + 1e-5f) * gam[r] + bet[r];
  }
  for (int i = t; i < RNUM_ * D2_; i += 256) Rs[i] = Rm[i];
  __syncthreads();
  for (int o = t; o < E_ * RNUM_; o += 256) {
    int je = o / RNUM_;
    int k = o % RNUM_;
    float s = 0.f;
    #pragma unroll
    for (int r = 0; r < D2_; ++r) s += zS[r * E_ + je] * Rs[k * D2_ + r];
    out[(size_t)blk * (E_ * RNUM_) + o] = s;
  }
}

extern "C" void kernel_launch(void* const* d_in, const int* in_sizes, int n_in,
                              void* d_out, int out_size, void* d_ws, size_t ws_size,
                              hipStream_t stream) {
  const float* enc  = (const float*)d_in[0];
  const int*  etype = (const int*)d_in[1];
  const int*  eidv  = (const int*)d_in[2];
  const int*  midv  = (const int*)d_in[3];
  const float* tbl  = (const float*)d_in[4];
  const float* temb = (const float*)d_in[5];
  const float* iemb = (const float*)d_in[6];
  const float* W    = (const float*)d_in[7];
  const float* Rm   = (const float*)d_in[8];
  const float* gam  = (const float*)d_in[9];
  const float* bet  = (const float*)d_in[10];
  const float* mu   = (const float*)d_in[11];
  const float* var  = (const float*)d_in[12];

  // ws layout: zpart | eswz | x
  float* ws    = (float*)d_ws;
  float* zpart = ws;                                           // 1,497,600 f
  short* eswz  = (short*)(zpart + (size_t)JT_ * MROWS_ * ZS_); // 159,744 sh
  float* x     = (float*)(eswz + (size_t)104 * MROWS_ * 8);    // 478,336 f
  float* out   = (float*)d_out;

  hipLaunchKernelGGL(k_mention_pool, dim3(B_ * NODES_), dim3(256), 0, stream,
                     enc, etype, eidv, midv, temb, iemb, x);
  hipLaunchKernelGGL(k_entity_pool, dim3(MROWS_), dim3(256), 0, stream,
                     x, tbl, eswz);
  hipLaunchKernelGGL(k_gemm, dim3(JT_, D2_), dim3(256), 0, stream,
                     W, eswz, zpart);
  hipLaunchKernelGGL(k_out, dim3(MROWS_), dim3(256), 0, stream,
                     zpart, Rm, gam, bet, mu, var, out);
}

// Round 17
// 120.893 us; speedup vs baseline: 2.1123x; 1.0474x over previous
//
#include <hip/hip_runtime.h>
#include <hip/hip_bf16.h>

#define B_ 16
#define S_ 512
#define H_ 768
#define TS_ 20
#define IS_ 20
#define D_ 808
#define M_ 36
#define E_ 12
#define RNUM_ 97
#define D2_ 50
#define P_ (E_*E_)        // 144
#define NODES_ (M_+1)     // 37
#define NCOL_ (D2_*D_)    // 40400
#define MROWS_ (B_*E_)    // 192
#define KSTEPS_ 26
#define KPAD_ (KSTEPS_*32)  // 832

typedef __attribute__((ext_vector_type(8))) short bf16x8;
typedef __attribute__((ext_vector_type(4))) float f32x4;

__device__ inline unsigned short f2bf(float f) {
  union { float f; unsigned u; } v; v.f = f;
  unsigned r = v.u + 0x7FFFu + ((v.u >> 16) & 1u);
  return (unsigned short)(r >> 16);
}

__device__ inline unsigned pack2bf(float a, float b) {
  union { __hip_bfloat162 h; unsigned u; } p;
  p.h = __float22bfloat162_rn(make_float2(a, b));
  return p.u;
}

// ---------------- kernel 1: mention mean-pooling (ballot version) ------------
__global__ __launch_bounds__(256) void k_mention_pool(
    const float* __restrict__ enc_hid, const int* __restrict__ etype,
    const int* __restrict__ eidv, const int* __restrict__ midv,
    const float* __restrict__ type_emb, const float* __restrict__ id_emb,
    float* __restrict__ x) {
  int blk = blockIdx.x;
  int b = blk / NODES_;
  int n = blk % NODES_;
  int t = threadIdx.x;
  float* xrow = x + (size_t)(b * NODES_ + n) * D_;
  if (n == 0) {
    for (int d = t; d < D_; d += 256)
      xrow[d] = (d < H_) ? enc_hid[(size_t)(b * S_) * H_ + d] : 0.0f;
    return;
  }
  __shared__ int midS[S_], tyS[S_], ivS[S_], list[S_];
  __shared__ int cntS;
  for (int s = t; s < S_; s += 256) {
    midS[s] = midv[b * S_ + s];
    tyS[s]  = etype[b * S_ + s];
    ivS[s]  = eidv[b * S_ + s];
  }
  __syncthreads();
  if (t < 64) {
    int base = 0;
    #pragma unroll
    for (int c = 0; c < 8; ++c) {
      int s = c * 64 + t;
      bool m = (midS[s] == n);
      unsigned long long bal = __ballot(m);
      int pos = base + __popcll(bal & ((1ULL << t) - 1ULL));
      if (m) list[pos] = s;
      base += __popcll(bal);
    }
    if (t == 0) cntS = base;
  }
  __syncthreads();
  int cnt = cntS;
  float a0 = 0.f, a1 = 0.f, a2 = 0.f, a3 = 0.f;
  for (int i = 0; i < cnt; ++i) {
    int s = list[i];
    const float* er = enc_hid + (size_t)(b * S_ + s) * H_;
    a0 += er[t];
    a1 += er[t + 256];
    a2 += er[t + 512];
    if (t < TS_ + IS_) {
      int ty = tyS[s], iv = ivS[s];
      a3 += (t < TS_) ? type_emb[ty * TS_ + t] : id_emb[iv * IS_ + (t - TS_)];
    }
  }
  float inv = (cnt > 0) ? 1.0f / (float)cnt : 0.0f;
  xrow[t] = a0 * inv;
  xrow[t + 256] = a1 * inv;
  xrow[t + 512] = a2 * inv;
  if (t < TS_ + IS_) xrow[H_ + t] = a3 * inv;
}

// ---------------- kernel 2: entity pooling -> bf16 pre-swizzled eswz ---------
__global__ __launch_bounds__(256) void k_entity_pool(
    const float* __restrict__ x, const float* __restrict__ tbl,
    short* __restrict__ eswz) {
  int blk = blockIdx.x;
  int b = blk / E_;
  int e = blk % E_;
  int t = threadIdx.x;
  const float* trow = tbl + (size_t)(b * (E_ + 1) + (e + 1)) * NODES_;
  __shared__ float w[NODES_];
  __shared__ float sinv;
  if (t < NODES_) w[t] = trow[t];
  __syncthreads();
  if (t == 0) {
    float s = 0.f;
    for (int m = 0; m < NODES_; ++m) s += w[m];
    sinv = (s > 0.f) ? 1.0f / s : 0.0f;
  }
  __syncthreads();
  float inv = sinv;
  for (int d = t; d < D_; d += 256) {
    float a = 0.f;
    for (int m = 0; m < NODES_; ++m)
      a += w[m] * x[(size_t)(b * NODES_ + m) * D_ + d];
    float v = a * inv;
    eswz[((size_t)(d >> 3) * MROWS_ + blk) * 8 + (d & 7)] = (short)f2bf(v);
  }
  if (t < KPAD_ - D_) {
    int d = D_ + t;
    eswz[((size_t)(d >> 3) * MROWS_ + blk) * 8 + (d & 7)] = 0;
  }
}

// ---------------- kernel 2b: W fp32 -> bf16 fragment-ready layout ------------
// Linear-ish both sides: reads 8 k-rows coalesced (1KB/wave chunks), writes
// Wbf[slice][c][8] contiguous (646 KB linear per slice).
__global__ __launch_bounds__(256) void k_wconv(
    const float* __restrict__ Wf, short* __restrict__ Wbf) {
  int slice = blockIdx.y;                 // 0..103
  int c = blockIdx.x * 256 + threadIdx.x;
  if (c >= NCOL_) return;
  int k0 = (slice >> 2) * 32 + (slice & 3) * 8;
  float v[8];
  #pragma unroll
  for (int e = 0; e < 8; ++e) {
    int k = k0 + e;
    v[e] = (k < D_) ? Wf[(size_t)k * NCOL_ + c] : 0.0f;
  }
  union { bf16x8 s; unsigned u[4]; } p;
  #pragma unroll
  for (int e2 = 0; e2 < 4; ++e2) p.u[e2] = pack2bf(v[2 * e2], v[2 * e2 + 1]);
  *(bf16x8*)&Wbf[((size_t)slice * NCOL_ + c) * 8] = p.s;
}

// ---------------- kernel 3: Abf[192,40400] = Ent @ Wview (bf16 in/out) -------
// BM=192 BN=64. No LDS, no barriers, no conversion in the K-loop:
// A-frags = dwordx4 from eswz (L2-hot), B-frags = dwordx4 from Wbf (streamed).
// 2-step ping-pong prefetch. Output stored as bf16.
__global__ __launch_bounds__(256) void k_gemm(
    const short* __restrict__ Wbf, const short* __restrict__ eswz,
    short* __restrict__ Abf) {
  const int tid = threadIdx.x;
  const int ln15 = tid & 15;
  const int g = (tid >> 4) & 3;
  const int wv = tid >> 6;
  const int colBase = blockIdx.x * 64;

  int col[4]; bool cok[4];
  #pragma unroll
  for (int nt = 0; nt < 4; ++nt) {
    int c = colBase + nt * 16 + ln15;
    cok[nt] = (c < NCOL_);
    col[nt] = cok[nt] ? c : (NCOL_ - 1);
  }

  f32x4 acc[3][4];
  #pragma unroll
  for (int i = 0; i < 3; ++i)
    #pragma unroll
    for (int j = 0; j < 4; ++j)
      acc[i][j] = (f32x4){0.f, 0.f, 0.f, 0.f};

  auto LOADA = [&](int t, bf16x8* af) {
    #pragma unroll
    for (int mt = 0; mt < 3; ++mt)
      af[mt] = *(const bf16x8*)&eswz[
          ((size_t)(t * 4 + g) * MROWS_ + wv * 48 + mt * 16 + ln15) * 8];
  };
  auto LOADB = [&](int t, bf16x8* bf) {
    #pragma unroll
    for (int nt = 0; nt < 4; ++nt)
      bf[nt] = *(const bf16x8*)&Wbf[((size_t)(t * 4 + g) * NCOL_ + col[nt]) * 8];
  };
  auto MM = [&](bf16x8* af, bf16x8* bf) {
    #pragma unroll
    for (int mt = 0; mt < 3; ++mt)
      #pragma unroll
      for (int nt = 0; nt < 4; ++nt)
        acc[mt][nt] = __builtin_amdgcn_mfma_f32_16x16x32_bf16(
            af[mt], bf[nt], acc[mt][nt], 0, 0, 0);
  };

  bf16x8 aA[3], bA[4], aB[3], bB[4];
  LOADA(0, aA); LOADB(0, bA);
  for (int t = 0; t < KSTEPS_; t += 2) {
    LOADA(t + 1, aB); LOADB(t + 1, bB);      // t+1 <= 25 always valid
    MM(aA, bA);
    if (t + 2 < KSTEPS_) { LOADA(t + 2, aA); LOADB(t + 2, bA); }
    MM(aB, bB);
  }

  // epilogue: C/D layout col = lane&15, row = g*4 + j; store bf16
  #pragma unroll
  for (int mt = 0; mt < 3; ++mt) {
    int row = wv * 48 + mt * 16 + g * 4;
    #pragma unroll
    for (int nt = 0; nt < 4; ++nt) {
      if (cok[nt]) {
        #pragma unroll
        for (int j = 0; j < 4; ++j)
          Abf[(size_t)(row + j) * NCOL_ + col[nt]] = (short)f2bf(acc[mt][nt][j]);
      }
    }
  }
}

// ---------------- kernel 4a: z via MFMA — one wave per (b, r) ---------------
__global__ __launch_bounds__(64) void k_score_z(
    const short* __restrict__ Abf, const short* __restrict__ eswz,
    float* __restrict__ zbuf) {
  int w = blockIdx.x;            // 0..799
  int b = w / D2_;
  int r = w % D2_;
  int lane = threadIdx.x;
  int ln15 = lane & 15;
  int g = lane >> 4;
  int m = b * E_ + ln15;
  if (m > MROWS_ - 1) m = MROWS_ - 1;
  const short* ab = Abf + (size_t)m * NCOL_ + (size_t)r * D_ + g * 8;
  const short* bb = eswz + ((size_t)g * MROWS_ + m) * 8;
  f32x4 acc = (f32x4){0.f, 0.f, 0.f, 0.f};
  #pragma unroll
  for (int t = 0; t < KSTEPS_; ++t) {
    bf16x8 af = *(const bf16x8*)(ab + t * 32);
    bf16x8 bf = *(const bf16x8*)(bb + (size_t)t * 4 * MROWS_ * 8);
    acc = __builtin_amdgcn_mfma_f32_16x16x32_bf16(af, bf, acc, 0, 0, 0);
  }
  if (ln15 < E_ && g < 3) {
    #pragma unroll
    for (int jj = 0; jj < 4; ++jj)
      zbuf[(size_t)(b * E_ + g * 4 + jj) * (D2_ * E_) + r * E_ + ln15] = acc[jj];
  }
}

// ---------------- kernel 4b: BN + R projection ------------------------------
__global__ __launch_bounds__(256) void k_out(
    const float* __restrict__ zbuf, const float* __restrict__ Rm,
    const float* __restrict__ gam, const float* __restrict__ bet,
    const float* __restrict__ mu, const float* __restrict__ var,
    float* __restrict__ out) {
  int blk = blockIdx.x;   // b*12+ke
  int t = threadIdx.x;
  __shared__ float zS[D2_ * E_];       // 600
  __shared__ float Rs[RNUM_ * D2_];    // 4850
  for (int i = t; i < D2_ * E_; i += 256) {
    int r = i / E_;
    float z = zbuf[(size_t)blk * (D2_ * E_) + i];
    zS[i] = (z - mu[r]) * rsqrtf(var[r] + 1e-5f) * gam[r] + bet[r];
  }
  for (int i = t; i < RNUM_ * D2_; i += 256) Rs[i] = Rm[i];
  __syncthreads();
  for (int o = t; o < E_ * RNUM_; o += 256) {
    int je = o / RNUM_;
    int k = o % RNUM_;
    float s = 0.f;
    #pragma unroll
    for (int r = 0; r < D2_; ++r) s += zS[r * E_ + je] * Rs[k * D2_ + r];
    out[(size_t)blk * (E_ * RNUM_) + o] = s;
  }
}

extern "C" void kernel_launch(void* const* d_in, const int* in_sizes, int n_in,
                              void* d_out, int out_size, void* d_ws, size_t ws_size,
                              hipStream_t stream) {
  const float* enc  = (const float*)d_in[0];
  const int*  etype = (const int*)d_in[1];
  const int*  eidv  = (const int*)d_in[2];
  const int*  midv  = (const int*)d_in[3];
  const float* tbl  = (const float*)d_in[4];
  const float* temb = (const float*)d_in[5];
  const float* iemb = (const float*)d_in[6];
  const float* W    = (const float*)d_in[7];
  const float* Rm   = (const float*)d_in[8];
  const float* gam  = (const float*)d_in[9];
  const float* bet  = (const float*)d_in[10];
  const float* mu   = (const float*)d_in[11];
  const float* var  = (const float*)d_in[12];

  // ws layout: zbuf | eswz | Abf | Wbf | x
  float* ws   = (float*)d_ws;
  float* zbuf = ws;                                           // 115,200 f
  short* eswz = (short*)(zbuf + (size_t)MROWS_ * D2_ * E_);   // 159,744 sh
  short* Abf  = eswz + (size_t)104 * MROWS_ * 8;              // 7,756,800 sh
  short* Wbf  = Abf + (size_t)MROWS_ * NCOL_;                 // 33,612,800 sh
  float* x    = (float*)(Wbf + (size_t)104 * NCOL_ * 8);      // 478,336 f
  float* out  = (float*)d_out;

  hipLaunchKernelGGL(k_mention_pool, dim3(B_ * NODES_), dim3(256), 0, stream,
                     enc, etype, eidv, midv, temb, iemb, x);
  hipLaunchKernelGGL(k_entity_pool, dim3(MROWS_), dim3(256), 0, stream,
                     x, tbl, eswz);
  hipLaunchKernelGGL(k_wconv, dim3((NCOL_ + 255) / 256, 104), dim3(256), 0,
                     stream, W, Wbf);
  hipLaunchKernelGGL(k_gemm, dim3((NCOL_ + 63) / 64), dim3(256), 0, stream,
                     Wbf, eswz, Abf);
  hipLaunchKernelGGL(k_score_z, dim3(B_ * D2_), dim3(64), 0, stream,
                     Abf, eswz, zbuf);
  hipLaunchKernelGGL(k_out, dim3(MROWS_), dim3(256), 0, stream,
                     zbuf, Rm, gam, bet, mu, var, out);
}

// Round 18
// 99.050 us; speedup vs baseline: 2.5781x; 1.2205x over previous
//
#include <hip/hip_runtime.h>
#include <hip/hip_bf16.h>

#define B_ 16
#define S_ 512
#define H_ 768
#define TS_ 20
#define IS_ 20
#define D_ 808
#define M_ 36
#define E_ 12
#define RNUM_ 97
#define D2_ 50
#define P_ (E_*E_)        // 144
#define NODES_ (M_+1)     // 37
#define NCOL_ (D2_*D_)    // 40400
#define MROWS_ (B_*E_)    // 192
#define KSTEPS_ 26
#define KPAD_ (KSTEPS_*32)  // 832
#define BLKPAD_ 1040        // 1024B (4 k-rows x 64 cols fp32) + 16B pad
#define TILEB_ (8*BLKPAD_)  // 8320 B per K-step tile

typedef __attribute__((ext_vector_type(8))) short bf16x8;
typedef __attribute__((ext_vector_type(4))) float f32x4;

__device__ inline unsigned short f2bf(float f) {
  union { float f; unsigned u; } v; v.f = f;
  unsigned r = v.u + 0x7FFFu + ((v.u >> 16) & 1u);
  return (unsigned short)(r >> 16);
}

__device__ inline unsigned pack2bf(float a, float b) {
  union { __hip_bfloat162 h; unsigned u; } p;
  p.h = __float22bfloat162_rn(make_float2(a, b));
  return p.u;
}

__device__ inline void gll16(const float* src, void* lds) {
  __builtin_amdgcn_global_load_lds(
      (const __attribute__((address_space(1))) unsigned int*)src,
      (__attribute__((address_space(3))) unsigned int*)lds, 16, 0, 0);
}

// ---------------- kernel 1: mention mean-pooling (+ cls node) ----------------
// Ballot-compaction (proven) + MLP-optimized accumulation: threads 0-191 own
// 4 dims via float4 (waves 0-2), wave 3 handles the 40 emb dims; token loop
// 4-way unrolled -> 4x16B outstanding loads/thread.
__global__ __launch_bounds__(256) void k_mention_pool(
    const float* __restrict__ enc_hid, const int* __restrict__ etype,
    const int* __restrict__ eidv, const int* __restrict__ midv,
    const float* __restrict__ type_emb, const float* __restrict__ id_emb,
    float* __restrict__ x) {
  int blk = blockIdx.x;
  int b = blk / NODES_;
  int n = blk % NODES_;
  int t = threadIdx.x;
  float* xrow = x + (size_t)(b * NODES_ + n) * D_;
  if (n == 0) {
    for (int d = t; d < D_; d += 256)
      xrow[d] = (d < H_) ? enc_hid[(size_t)(b * S_) * H_ + d] : 0.0f;
    return;
  }
  __shared__ int midS[S_], tyS[S_], ivS[S_], list[S_];
  __shared__ int cntS;
  for (int s = t; s < S_; s += 256) {
    midS[s] = midv[b * S_ + s];
    tyS[s]  = etype[b * S_ + s];
    ivS[s]  = eidv[b * S_ + s];
  }
  __syncthreads();
  if (t < 64) {   // wave 0: ordered compaction via ballot
    int base = 0;
    #pragma unroll
    for (int c = 0; c < 8; ++c) {
      int s = c * 64 + t;
      bool m = (midS[s] == n);
      unsigned long long bal = __ballot(m);
      int pos = base + __popcll(bal & ((1ULL << t) - 1ULL));
      if (m) list[pos] = s;
      base += __popcll(bal);
    }
    if (t == 0) cntS = base;
  }
  __syncthreads();
  int cnt = cntS;
  const float* encB = enc_hid + (size_t)(b * S_) * H_;
  float4 a = make_float4(0.f, 0.f, 0.f, 0.f);
  float aemb = 0.f;
  int tt = t - 192;
  int i = 0;
  for (; i + 4 <= cnt; i += 4) {
    int s0 = list[i], s1 = list[i + 1], s2 = list[i + 2], s3 = list[i + 3];
    if (t < 192) {
      float4 v0 = *(const float4*)(encB + (size_t)s0 * H_ + 4 * t);
      float4 v1 = *(const float4*)(encB + (size_t)s1 * H_ + 4 * t);
      float4 v2 = *(const float4*)(encB + (size_t)s2 * H_ + 4 * t);
      float4 v3 = *(const float4*)(encB + (size_t)s3 * H_ + 4 * t);
      a.x += v0.x + v1.x + v2.x + v3.x;
      a.y += v0.y + v1.y + v2.y + v3.y;
      a.z += v0.z + v1.z + v2.z + v3.z;
      a.w += v0.w + v1.w + v2.w + v3.w;
    } else if (tt < TS_ + IS_) {
      #pragma unroll
      for (int q = 0; q < 4; ++q) {
        int s = list[i + q];
        aemb += (tt < TS_) ? type_emb[tyS[s] * TS_ + tt]
                           : id_emb[ivS[s] * IS_ + (tt - TS_)];
      }
    }
  }
  for (; i < cnt; ++i) {
    int s = list[i];
    if (t < 192) {
      float4 v = *(const float4*)(encB + (size_t)s * H_ + 4 * t);
      a.x += v.x; a.y += v.y; a.z += v.z; a.w += v.w;
    } else if (tt < TS_ + IS_) {
      aemb += (tt < TS_) ? type_emb[tyS[s] * TS_ + tt]
                         : id_emb[ivS[s] * IS_ + (tt - TS_)];
    }
  }
  float inv = (cnt > 0) ? 1.0f / (float)cnt : 0.0f;
  if (t < 192) {
    float4 r = make_float4(a.x * inv, a.y * inv, a.z * inv, a.w * inv);
    *(float4*)(xrow + 4 * t) = r;
  } else if (tt < TS_ + IS_) {
    xrow[H_ + tt] = aemb * inv;
  }
}

// ---------------- kernel 2: entity pooling -> bf16 pre-swizzled eswz ---------
__global__ __launch_bounds__(256) void k_entity_pool(
    const float* __restrict__ x, const float* __restrict__ tbl,
    short* __restrict__ eswz) {
  int blk = blockIdx.x;
  int b = blk / E_;
  int e = blk % E_;
  int t = threadIdx.x;
  const float* trow = tbl + (size_t)(b * (E_ + 1) + (e + 1)) * NODES_;
  __shared__ float w[NODES_];
  __shared__ float sinv;
  if (t < NODES_) w[t] = trow[t];
  __syncthreads();
  if (t == 0) {
    float s = 0.f;
    for (int m = 0; m < NODES_; ++m) s += w[m];
    sinv = (s > 0.f) ? 1.0f / s : 0.0f;
  }
  __syncthreads();
  float inv = sinv;
  for (int d = t; d < D_; d += 256) {
    float a = 0.f;
    for (int m = 0; m < NODES_; ++m)
      a += w[m] * x[(size_t)(b * NODES_ + m) * D_ + d];
    float v = a * inv;
    eswz[((size_t)(d >> 3) * MROWS_ + blk) * 8 + (d & 7)] = (short)f2bf(v);
  }
  if (t < KPAD_ - D_) {   // zero-pad k = 808..831
    int d = D_ + t;
    eswz[((size_t)(d >> 3) * MROWS_ + blk) * 8 + (d & 7)] = 0;
  }
}

// ---------------- kernel 3: Abf[192,40400] = Ent @ Wview (fused, 1 W pass) ---
__global__ __launch_bounds__(256) void k_gemm(
    const float* __restrict__ Wf, const short* __restrict__ eswz,
    short* __restrict__ Abf) {
  __shared__ __align__(16) char Bs[3 * TILEB_];   // 24.96 KiB
  const int tid = threadIdx.x;
  const int lane = tid & 63;
  const int ln15 = lane & 15;
  const int g = (lane >> 4) & 3;
  const int wv = tid >> 6;
  const int wr = wv >> 1;          // 0..1: row half (96 rows)
  const int wc = wv & 1;           // 0..1: col half (32 cols)
  const int colBase = blockIdx.x * 64;

  f32x4 acc[6][2];
  #pragma unroll
  for (int i = 0; i < 6; ++i)
    #pragma unroll
    for (int j = 0; j < 2; ++j)
      acc[i][j] = (f32x4){0.f, 0.f, 0.f, 0.f};

  auto STAGE = [&](int t, int bufi) {
    #pragma unroll
    for (int r2 = 0; r2 < 2; ++r2) {
      int bi = r2 * 4 + wv;
      int kg = t * 32 + bi * 4 + (lane >> 4);
      if (kg > D_ - 1) kg = D_ - 1;
      int cg = colBase + ln15 * 4;
      if (cg > NCOL_ - 4) cg = NCOL_ - 4;
      gll16(Wf + (size_t)kg * NCOL_ + cg, Bs + bufi * TILEB_ + bi * BLKPAD_);
    }
  };

  STAGE(0, 0);
  STAGE(1, 1);
  __syncthreads();

  int rb = 0;
  for (int t = 0; t < KSTEPS_; ++t) {
    int sb = rb + 2; if (sb >= 3) sb -= 3;
    if (t + 2 < KSTEPS_) STAGE(t + 2, sb);
    const char* bb = Bs + rb * TILEB_;
    bf16x8 bfr[2];
    #pragma unroll
    for (int nt = 0; nt < 2; ++nt) {
      float f[8];
      #pragma unroll
      for (int e = 0; e < 8; ++e) {
        int k = g * 8 + e;
        int col = wc * 32 + nt * 16 + ln15;
        f[e] = *(const float*)(bb + (k >> 2) * BLKPAD_ + (k & 3) * 256 + col * 4);
      }
      union { bf16x8 v; unsigned u[4]; } u;
      #pragma unroll
      for (int e2 = 0; e2 < 4; ++e2)
        u.u[e2] = pack2bf(f[2 * e2], f[2 * e2 + 1]);
      bfr[nt] = u.v;
    }
    bf16x8 af[6];
    #pragma unroll
    for (int mt = 0; mt < 6; ++mt)
      af[mt] = *(const bf16x8*)&eswz[
          ((size_t)(t * 4 + g) * MROWS_ + wr * 96 + mt * 16 + ln15) * 8];
    #pragma unroll
    for (int mt = 0; mt < 6; ++mt)
      #pragma unroll
      for (int nt = 0; nt < 2; ++nt)
        acc[mt][nt] = __builtin_amdgcn_mfma_f32_16x16x32_bf16(
            af[mt], bfr[nt], acc[mt][nt], 0, 0, 0);
    __syncthreads();
    rb = (rb == 2) ? 0 : rb + 1;
  }

  #pragma unroll
  for (int mt = 0; mt < 6; ++mt) {
    int row = wr * 96 + mt * 16 + g * 4;
    #pragma unroll
    for (int nt = 0; nt < 2; ++nt) {
      int col = colBase + wc * 32 + nt * 16 + ln15;
      if (col < NCOL_) {
        #pragma unroll
        for (int j = 0; j < 4; ++j)
          Abf[(size_t)(row + j) * NCOL_ + col] = (short)f2bf(acc[mt][nt][j]);
      }
    }
  }
}

// ---------------- kernel 4a: z via MFMA — one wave per (b, r) ---------------
__global__ __launch_bounds__(64) void k_score_z(
    const short* __restrict__ Abf, const short* __restrict__ eswz,
    float* __restrict__ zbuf) {
  int w = blockIdx.x;            // 0..799
  int b = w / D2_;
  int r = w % D2_;
  int lane = threadIdx.x;
  int ln15 = lane & 15;
  int g = lane >> 4;
  int m = b * E_ + ln15;
  if (m > MROWS_ - 1) m = MROWS_ - 1;
  const short* ab = Abf + (size_t)m * NCOL_ + (size_t)r * D_ + g * 8;
  const short* bb = eswz + ((size_t)g * MROWS_ + m) * 8;
  f32x4 acc = (f32x4){0.f, 0.f, 0.f, 0.f};
  #pragma unroll
  for (int t = 0; t < KSTEPS_; ++t) {
    bf16x8 af = *(const bf16x8*)(ab + t * 32);
    bf16x8 bf = *(const bf16x8*)(bb + (size_t)t * 4 * MROWS_ * 8);
    acc = __builtin_amdgcn_mfma_f32_16x16x32_bf16(af, bf, acc, 0, 0, 0);
  }
  if (ln15 < E_ && g < 3) {
    #pragma unroll
    for (int jj = 0; jj < 4; ++jj)
      zbuf[(size_t)(b * E_ + g * 4 + jj) * (D2_ * E_) + r * E_ + ln15] = acc[jj];
  }
}

// ---------------- kernel 4b: BN + R projection ------------------------------
__global__ __launch_bounds__(256) void k_out(
    const float* __restrict__ zbuf, const float* __restrict__ Rm,
    const float* __restrict__ gam, const float* __restrict__ bet,
    const float* __restrict__ mu, const float* __restrict__ var,
    float* __restrict__ out) {
  int blk = blockIdx.x;   // b*12+ke
  int t = threadIdx.x;
  __shared__ float zS[D2_ * E_];       // 600
  __shared__ float Rs[RNUM_ * D2_];    // 4850
  for (int i = t; i < D2_ * E_; i += 256) {
    int r = i / E_;
    float z = zbuf[(size_t)blk * (D2_ * E_) + i];
    zS[i] = (z - mu[r]) * rsqrtf(var[r] + 1e-5f) * gam[r] + bet[r];
  }
  for (int i = t; i < RNUM_ * D2_; i += 256) Rs[i] = Rm[i];
  __syncthreads();
  for (int o = t; o < E_ * RNUM_; o += 256) {
    int je = o / RNUM_;
    int k = o % RNUM_;
    float s = 0.f;
    #pragma unroll
    for (int r = 0; r < D2_; ++r) s += zS[r * E_ + je] * Rs[k * D2_ + r];
    out[(size_t)blk * (E_ * RNUM_) + o] = s;
  }
}

extern "C" void kernel_launch(void* const* d_in, const int* in_sizes, int n_in,
                              void* d_out, int out_size, void* d_ws, size_t ws_size,
                              hipStream_t stream) {
  const float* enc  = (const float*)d_in[0];
  const int*  etype = (const int*)d_in[1];
  const int*  eidv  = (const int*)d_in[2];
  const int*  midv  = (const int*)d_in[3];
  const float* tbl  = (const float*)d_in[4];
  const float* temb = (const float*)d_in[5];
  const float* iemb = (const float*)d_in[6];
  const float* W    = (const float*)d_in[7];
  const float* Rm   = (const float*)d_in[8];
  const float* gam  = (const float*)d_in[9];
  const float* bet  = (const float*)d_in[10];
  const float* mu   = (const float*)d_in[11];
  const float* var  = (const float*)d_in[12];

  // ws layout: zbuf | eswz | Abf | x
  float* ws   = (float*)d_ws;
  float* zbuf = ws;                                           // 115,200 f
  short* eswz = (short*)(zbuf + (size_t)MROWS_ * D2_ * E_);   // 159,744 sh
  short* Abf  = eswz + (size_t)104 * MROWS_ * 8;              // 7,756,800 sh
  float* x    = (float*)(Abf + (size_t)MROWS_ * NCOL_);       // 478,336 f
  float* out  = (float*)d_out;

  hipLaunchKernelGGL(k_mention_pool, dim3(B_ * NODES_), dim3(256), 0, stream,
                     enc, etype, eidv, midv, temb, iemb, x);
  hipLaunchKernelGGL(k_entity_pool, dim3(MROWS_), dim3(256), 0, stream,
                     x, tbl, eswz);
  hipLaunchKernelGGL(k_gemm, dim3((NCOL_ + 63) / 64), dim3(256), 0, stream,
                     W, eswz, Abf);
  hipLaunchKernelGGL(k_score_z, dim3(B_ * D2_), dim3(64), 0, stream,
                     Abf, eswz, zbuf);
  hipLaunchKernelGGL(k_out, dim3(MROWS_), dim3(256), 0, stream,
                     zbuf, Rm, gam, bet, mu, var, out);
}

// Round 19
// 82.006 us; speedup vs baseline: 3.1139x; 1.2078x over previous
//
#include <hip/hip_runtime.h>
#include <hip/hip_bf16.h>

#define B_ 16
#define S_ 512
#define H_ 768
#define TS_ 20
#define IS_ 20
#define D_ 808
#define M_ 36
#define E_ 12
#define RNUM_ 97
#define D2_ 50
#define P_ (E_*E_)        // 144
#define NODES_ (M_+1)     // 37
#define NCOL_ (D2_*D_)    // 40400
#define MROWS_ (B_*E_)    // 192
#define KSTEPS_ 26
#define KPAD_ (KSTEPS_*32)  // 832
#define BLKPAD_ 1040        // 1024B (4 k-rows x 64 cols fp32) + 16B pad
#define TILEB_ (8*BLKPAD_)  // 8320 B per K-step tile
#define TC_ 8               // token chunks (64 tokens each)

typedef __attribute__((ext_vector_type(8))) short bf16x8;
typedef __attribute__((ext_vector_type(4))) float f32x4;

__device__ inline unsigned short f2bf(float f) {
  union { float f; unsigned u; } v; v.f = f;
  unsigned r = v.u + 0x7FFFu + ((v.u >> 16) & 1u);
  return (unsigned short)(r >> 16);
}

__device__ inline unsigned pack2bf(float a, float b) {
  union { __hip_bfloat162 h; unsigned u; } p;
  p.h = __float22bfloat162_rn(make_float2(a, b));
  return p.u;
}

__device__ inline void gll16(const float* src, void* lds) {
  __builtin_amdgcn_global_load_lds(
      (const __attribute__((address_space(1))) unsigned int*)src,
      (__attribute__((address_space(3))) unsigned int*)lds, 16, 0, 0);
}

// ---------------- kernel 1: token-parallel fused pooling (partials) ----------
// Algebra (verified round 14): ent[b,e,:] = wcls_e*cls + sum_s w_e[s]*encC[s,:]
//   w_e[s] = tblN[e+1, mid[s]] / cnt[mid[s]]  (0 if mid=0 or cnt=0)
// Block (tc, b): 64 tokens; all 12 e accumulated per enc read.
__global__ __launch_bounds__(256) void k_pool(
    const float* __restrict__ enc, const int* __restrict__ etype,
    const int* __restrict__ eidv, const int* __restrict__ midv,
    const float* __restrict__ tbl, const float* __restrict__ temb,
    const float* __restrict__ iemb, float* __restrict__ partial) {
  int tc = blockIdx.x;
  int b  = blockIdx.y;
  int t  = threadIdx.x;
  __shared__ int midS[S_];
  __shared__ int cntS[NODES_];
  __shared__ int tyC[64], ivC[64];
  __shared__ float tblS[E_][NODES_];
  __shared__ float wtab[E_][40];      // [e][node], wtab[e][0]=0
  __shared__ float wclsS[E_];
  __shared__ float invTS[E_];

  for (int i = t; i < NODES_; i += 256) cntS[i] = 0;
  __syncthreads();
  for (int s = t; s < S_; s += 256) {
    int m = midv[b * S_ + s];
    midS[s] = m;
    atomicAdd(&cntS[m], 1);
  }
  if (t < 64) {
    int s = tc * 64 + t;
    tyC[t] = etype[b * S_ + s];
    ivC[t] = eidv[b * S_ + s];
  }
  for (int i = t; i < E_ * NODES_; i += 256) {
    int e = i / NODES_, n = i % NODES_;
    tblS[e][n] = tbl[(size_t)(b * (E_ + 1) + (e + 1)) * NODES_ + n];
  }
  __syncthreads();
  if (t < E_) {
    float s = 0.f;
    for (int n = 0; n < NODES_; ++n) s += tblS[t][n];
    invTS[t] = (s > 0.f) ? 1.0f / s : 1.0f;
    wclsS[t] = tblS[t][0] * invTS[t];
  }
  __syncthreads();
  for (int i = t; i < E_ * NODES_; i += 256) {
    int e = i / NODES_, n = i % NODES_;
    wtab[e][n] = (n >= 1 && cntS[n] > 0)
                     ? tblS[e][n] * invTS[e] / (float)cntS[n] : 0.0f;
  }
  __syncthreads();

  const float* encB = enc + (size_t)(b * S_) * H_;
  if (t < 192) {
    // acc[e] over 4 dims (float4 at 4t)
    f32x4 acc[E_];
    if (tc == 0) {
      float4 c = *(const float4*)(encB + 4 * t);
      #pragma unroll
      for (int e = 0; e < E_; ++e) {
        float w = wclsS[e];
        acc[e] = (f32x4){w * c.x, w * c.y, w * c.z, w * c.w};
      }
    } else {
      #pragma unroll
      for (int e = 0; e < E_; ++e) acc[e] = (f32x4){0.f, 0.f, 0.f, 0.f};
    }
    #pragma unroll 4
    for (int s = 0; s < 64; ++s) {
      int m = midS[tc * 64 + s];
      float4 v = *(const float4*)(encB + (size_t)(tc * 64 + s) * H_ + 4 * t);
      #pragma unroll
      for (int e = 0; e < E_; ++e) {
        float w = wtab[e][m];
        acc[e][0] += w * v.x;
        acc[e][1] += w * v.y;
        acc[e][2] += w * v.z;
        acc[e][3] += w * v.w;
      }
    }
    float* prow = partial + (size_t)(tc * MROWS_ + b * E_) * D_;
    #pragma unroll
    for (int e = 0; e < E_; ++e)
      *(f32x4*)(prow + (size_t)e * D_ + 4 * t) = acc[e];
  } else if (t - 192 < TS_ + IS_) {
    int tt = t - 192;
    float acc[E_];
    #pragma unroll
    for (int e = 0; e < E_; ++e) acc[e] = 0.f;
    for (int s = 0; s < 64; ++s) {
      int m = midS[tc * 64 + s];
      float val = (tt < TS_) ? temb[tyC[s] * TS_ + tt]
                             : iemb[ivC[s] * IS_ + (tt - TS_)];
      #pragma unroll
      for (int e = 0; e < E_; ++e) acc[e] += wtab[e][m] * val;
    }
    float* prow = partial + (size_t)(tc * MROWS_ + b * E_) * D_;
    #pragma unroll
    for (int e = 0; e < E_; ++e) prow[(size_t)e * D_ + H_ + tt] = acc[e];
  }
}

// ---------------- kernel 1b: reduce partials -> bf16 pre-swizzled eswz -------
__global__ __launch_bounds__(256) void k_entred(
    const float* __restrict__ partial, short* __restrict__ eswz) {
  int row = blockIdx.x;   // 0..191
  int t = threadIdx.x;
  for (int d = t; d < D_; d += 256) {
    float s = 0.f;
    #pragma unroll
    for (int tc = 0; tc < TC_; ++tc)
      s += partial[((size_t)tc * MROWS_ + row) * D_ + d];
    eswz[((size_t)(d >> 3) * MROWS_ + row) * 8 + (d & 7)] = (short)f2bf(s);
  }
  if (t < KPAD_ - D_) {
    int d = D_ + t;
    eswz[((size_t)(d >> 3) * MROWS_ + row) * 8 + (d & 7)] = 0;
  }
}

// ---------------- kernel 2: Abf[192,40400] = Ent @ Wview (fused, 1 W pass) ---
__global__ __launch_bounds__(256) void k_gemm(
    const float* __restrict__ Wf, const short* __restrict__ eswz,
    short* __restrict__ Abf) {
  __shared__ __align__(16) char Bs[3 * TILEB_];   // 24.96 KiB
  const int tid = threadIdx.x;
  const int lane = tid & 63;
  const int ln15 = lane & 15;
  const int g = (lane >> 4) & 3;
  const int wv = tid >> 6;
  const int wr = wv >> 1;          // 0..1: row half (96 rows)
  const int wc = wv & 1;           // 0..1: col half (32 cols)
  const int colBase = blockIdx.x * 64;

  f32x4 acc[6][2];
  #pragma unroll
  for (int i = 0; i < 6; ++i)
    #pragma unroll
    for (int j = 0; j < 2; ++j)
      acc[i][j] = (f32x4){0.f, 0.f, 0.f, 0.f};

  auto STAGE = [&](int t, int bufi) {
    #pragma unroll
    for (int r2 = 0; r2 < 2; ++r2) {
      int bi = r2 * 4 + wv;
      int kg = t * 32 + bi * 4 + (lane >> 4);
      if (kg > D_ - 1) kg = D_ - 1;
      int cg = colBase + ln15 * 4;
      if (cg > NCOL_ - 4) cg = NCOL_ - 4;
      gll16(Wf + (size_t)kg * NCOL_ + cg, Bs + bufi * TILEB_ + bi * BLKPAD_);
    }
  };

  STAGE(0, 0);
  STAGE(1, 1);
  __syncthreads();

  int rb = 0;
  for (int t = 0; t < KSTEPS_; ++t) {
    int sb = rb + 2; if (sb >= 3) sb -= 3;
    if (t + 2 < KSTEPS_) STAGE(t + 2, sb);
    const char* bb = Bs + rb * TILEB_;
    bf16x8 bfr[2];
    #pragma unroll
    for (int nt = 0; nt < 2; ++nt) {
      float f[8];
      #pragma unroll
      for (int e = 0; e < 8; ++e) {
        int k = g * 8 + e;
        int col = wc * 32 + nt * 16 + ln15;
        f[e] = *(const float*)(bb + (k >> 2) * BLKPAD_ + (k & 3) * 256 + col * 4);
      }
      union { bf16x8 v; unsigned u[4]; } u;
      #pragma unroll
      for (int e2 = 0; e2 < 4; ++e2)
        u.u[e2] = pack2bf(f[2 * e2], f[2 * e2 + 1]);
      bfr[nt] = u.v;
    }
    bf16x8 af[6];
    #pragma unroll
    for (int mt = 0; mt < 6; ++mt)
      af[mt] = *(const bf16x8*)&eswz[
          ((size_t)(t * 4 + g) * MROWS_ + wr * 96 + mt * 16 + ln15) * 8];
    #pragma unroll
    for (int mt = 0; mt < 6; ++mt)
      #pragma unroll
      for (int nt = 0; nt < 2; ++nt)
        acc[mt][nt] = __builtin_amdgcn_mfma_f32_16x16x32_bf16(
            af[mt], bfr[nt], acc[mt][nt], 0, 0, 0);
    __syncthreads();
    rb = (rb == 2) ? 0 : rb + 1;
  }

  #pragma unroll
  for (int mt = 0; mt < 6; ++mt) {
    int row = wr * 96 + mt * 16 + g * 4;
    #pragma unroll
    for (int nt = 0; nt < 2; ++nt) {
      int col = colBase + wc * 32 + nt * 16 + ln15;
      if (col < NCOL_) {
        #pragma unroll
        for (int j = 0; j < 4; ++j)
          Abf[(size_t)(row + j) * NCOL_ + col] = (short)f2bf(acc[mt][nt][j]);
      }
    }
  }
}

// ---------------- kernel 3: z via MFMA — one wave per (b, r) ---------------
__global__ __launch_bounds__(64) void k_score_z(
    const short* __restrict__ Abf, const short* __restrict__ eswz,
    float* __restrict__ zbuf) {
  int w = blockIdx.x;            // 0..799
  int b = w / D2_;
  int r = w % D2_;
  int lane = threadIdx.x;
  int ln15 = lane & 15;
  int g = lane >> 4;
  int m = b * E_ + ln15;
  if (m > MROWS_ - 1) m = MROWS_ - 1;
  const short* ab = Abf + (size_t)m * NCOL_ + (size_t)r * D_ + g * 8;
  const short* bb = eswz + ((size_t)g * MROWS_ + m) * 8;
  f32x4 acc = (f32x4){0.f, 0.f, 0.f, 0.f};
  #pragma unroll
  for (int t = 0; t < KSTEPS_; ++t) {
    bf16x8 af = *(const bf16x8*)(ab + t * 32);
    bf16x8 bf = *(const bf16x8*)(bb + (size_t)t * 4 * MROWS_ * 8);
    acc = __builtin_amdgcn_mfma_f32_16x16x32_bf16(af, bf, acc, 0, 0, 0);
  }
  if (ln15 < E_ && g < 3) {
    #pragma unroll
    for (int jj = 0; jj < 4; ++jj)
      zbuf[(size_t)(b * E_ + g * 4 + jj) * (D2_ * E_) + r * E_ + ln15] = acc[jj];
  }
}

// ---------------- kernel 4: BN + R projection ------------------------------
__global__ __launch_bounds__(256) void k_out(
    const float* __restrict__ zbuf, const float* __restrict__ Rm,
    const float* __restrict__ gam, const float* __restrict__ bet,
    const float* __restrict__ mu, const float* __restrict__ var,
    float* __restrict__ out) {
  int blk = blockIdx.x;   // b*12+ke
  int t = threadIdx.x;
  __shared__ float zS[D2_ * E_];       // 600
  __shared__ float Rs[RNUM_ * D2_];    // 4850
  for (int i = t; i < D2_ * E_; i += 256) {
    int r = i / E_;
    float z = zbuf[(size_t)blk * (D2_ * E_) + i];
    zS[i] = (z - mu[r]) * rsqrtf(var[r] + 1e-5f) * gam[r] + bet[r];
  }
  for (int i = t; i < RNUM_ * D2_; i += 256) Rs[i] = Rm[i];
  __syncthreads();
  for (int o = t; o < E_ * RNUM_; o += 256) {
    int je = o / RNUM_;
    int k = o % RNUM_;
    float s = 0.f;
    #pragma unroll
    for (int r = 0; r < D2_; ++r) s += zS[r * E_ + je] * Rs[k * D2_ + r];
    out[(size_t)blk * (E_ * RNUM_) + o] = s;
  }
}

extern "C" void kernel_launch(void* const* d_in, const int* in_sizes, int n_in,
                              void* d_out, int out_size, void* d_ws, size_t ws_size,
                              hipStream_t stream) {
  const float* enc  = (const float*)d_in[0];
  const int*  etype = (const int*)d_in[1];
  const int*  eidv  = (const int*)d_in[2];
  const int*  midv  = (const int*)d_in[3];
  const float* tbl  = (const float*)d_in[4];
  const float* temb = (const float*)d_in[5];
  const float* iemb = (const float*)d_in[6];
  const float* W    = (const float*)d_in[7];
  const float* Rm   = (const float*)d_in[8];
  const float* gam  = (const float*)d_in[9];
  const float* bet  = (const float*)d_in[10];
  const float* mu   = (const float*)d_in[11];
  const float* var  = (const float*)d_in[12];

  // ws layout: zbuf | eswz | Abf | partial
  float* ws    = (float*)d_ws;
  float* zbuf  = ws;                                           // 115,200 f
  short* eswz  = (short*)(zbuf + (size_t)MROWS_ * D2_ * E_);   // 159,744 sh
  short* Abf   = eswz + (size_t)104 * MROWS_ * 8;              // 7,756,800 sh
  float* partial = (float*)(Abf + (size_t)MROWS_ * NCOL_);     // 1,241,088 f
  float* out   = (float*)d_out;

  hipLaunchKernelGGL(k_pool, dim3(TC_, B_), dim3(256), 0, stream,
                     enc, etype, eidv, midv, tbl, temb, iemb, partial);
  hipLaunchKernelGGL(k_entred, dim3(MROWS_), dim3(256), 0, stream,
                     partial, eswz);
  hipLaunchKernelGGL(k_gemm, dim3((NCOL_ + 63) / 64), dim3(256), 0, stream,
                     W, eswz, Abf);
  hipLaunchKernelGGL(k_score_z, dim3(B_ * D2_), dim3(64), 0, stream,
                     Abf, eswz, zbuf);
  hipLaunchKernelGGL(k_out, dim3(MROWS_), dim3(256), 0, stream,
                     zbuf, Rm, gam, bet, mu, var, out);
}